// Round 2
// baseline (127.428 us; speedup 1.0000x reference)
//
#include <hip/hip_runtime.h>
#include <hip/hip_bf16.h>

// KPConv fused kernel for MI355X (gfx950) — round 2.
// B=4, M=16384, K_NB=32, D_IN=64, D_OUT=64, K_PTS=15, SIGMA=1.
//
// Stage 1 (per point): h[k][p] = max(0, 1-|r_k - Q_p|), Fk = h^T · Fn  (1 MFMA per d-tile)
// Stage 2 (per 16-pt tile): out = Fk · W, K=960 = 30 MFMA k-steps, W resident in 120 VGPR/wave.
//
// R2 changes vs R1: F pre-converted to bf16 in ws (halves gather bytes; batch slice
// 2.1 MB fits one XCD L2); XCD-aware block->point mapping; 1024 blocks x 64 pts
// (4 blocks/CU); whole-tile staging of (r, idx) to break per-point LDS WAR serialization;
// write-side fk swizzle improved with ^(p&7).

#define BATCH 4
#define MPTS  16384
#define KNB   32
#define DIN   64
#define DOUT  64
#define KP    15
#define K2    (KP*DIN)      // 960
#define KSTEPS (K2/32)      // 30
#define ROWBYTES (K2*2)     // 1920 bytes per Fk row (bf16)
#define PTS   (BATCH*MPTS)  // 65536
#define PPB   64            // points per block
#define NBLK  (PTS/PPB)     // 1024
#define NTILE (PPB/16)      // 4
#define WBELEMS (KP*DIN*DOUT)   // 61440 ushorts = 122880 B

typedef __bf16 bf16x8 __attribute__((ext_vector_type(8)));
typedef float  f32x4  __attribute__((ext_vector_type(4)));
typedef unsigned short u16x8 __attribute__((ext_vector_type(8)));

static __device__ __forceinline__ unsigned short f2b(float x) {
    __bf16 h = (__bf16)x;              // RNE convert
    return __builtin_bit_cast(unsigned short, h);
}

static __device__ __forceinline__ __bf16 loadF(const float* F, size_t i) {
    return (__bf16)F[i];
}
static __device__ __forceinline__ __bf16 loadF(const unsigned short* F, size_t i) {
    return __builtin_bit_cast(__bf16, F[i]);
}

// ---- prep: W [15][64][64] f32 -> bf16 B-fragments in ws ----
// wb[((etile*KSTEPS + kstep)*64 + lane)*8 + i] = W[k=kstep*32+(lane>>4)*8+i][e=etile*16+(lane&15)]
__global__ void prep_wb(const float* __restrict__ W, unsigned short* __restrict__ wb) {
    int idx = blockIdx.x * 256 + threadIdx.x;
    if (idx >= WBELEMS) return;
    int i    = idx & 7;
    int lane = (idx >> 3) & 63;
    int ks   = (idx >> 9) % KSTEPS;
    int et   = idx / (KSTEPS * 512);
    int k = ks * 32 + (lane >> 4) * 8 + i;
    int p = k >> 6;
    int d = k & 63;
    int e = et * 16 + (lane & 15);
    wb[idx] = f2b(W[(p * DIN + d) * DOUT + e]);
}

// ---- prep: F f32 -> bf16 (8 elems / thread) ----
__global__ void f2bf_kernel(const float* __restrict__ src, unsigned short* __restrict__ dst, int n8) {
    int i = blockIdx.x * 256 + threadIdx.x;
    if (i >= n8) return;
    const float4* s = reinterpret_cast<const float4*>(src) + (size_t)i * 2;
    float4 a = s[0], b = s[1];
    u16x8 o;
    o[0] = f2b(a.x); o[1] = f2b(a.y); o[2] = f2b(a.z); o[3] = f2b(a.w);
    o[4] = f2b(b.x); o[5] = f2b(b.y); o[6] = f2b(b.z); o[7] = f2b(b.w);
    *(reinterpret_cast<u16x8*>(dst) + i) = o;
}

template<typename FT>
__global__ __launch_bounds__(256, 4)
void kpconv_main(const float* __restrict__ X, const FT* __restrict__ F,
                 const int* __restrict__ NB, const float* __restrict__ Q,
                 const unsigned short* __restrict__ WB, float* __restrict__ OUT) {
    __shared__ float4 stg[4][4][KNB];         // [wave][point j][nb]: (rx,ry,rz, idx-bits)
    __shared__ unsigned short fk[16 * K2];    // 16 Fk rows, bf16, XOR-swizzled 16B chunks

    const int tid  = threadIdx.x;
    const int wv   = tid >> 6;    // wave 0..3 = e-tile
    const int lane = tid & 63;
    const int g16  = lane >> 4;   // 0..3
    const int r16  = lane & 15;   // 0..15

    // W B-fragments for this wave's e-tile: 30 x 16B = 120 VGPRs, resident all kernel
    bf16x8 bw[KSTEPS];
    {
        const unsigned short* base = WB + ((size_t)(wv * KSTEPS) * 64 + lane) * 8;
        #pragma unroll
        for (int ks = 0; ks < KSTEPS; ++ks)
            bw[ks] = *reinterpret_cast<const bf16x8*>(base + ks * 512);
    }

    // per-lane kernel-point constants (stage-1 A row p = r16; p=15 is the zero pad row)
    float qx = 0.f, qy = 0.f, qz = 0.f;
    const bool pvalid = (r16 < KP);
    if (pvalid) {
        qx = Q[r16 * 3 + 0]; qy = Q[r16 * 3 + 1]; qz = Q[r16 * 3 + 2];
    }

    // XCD-aware mapping: XCD (bid&7) owns points [xcd*8192, xcd*8192+8192) -> one batch/XCD
    const int bid     = blockIdx.x;
    const int base_pt = (bid & 7) * (PTS / 8) + (bid >> 3) * PPB;

    for (int tile = 0; tile < NTILE; ++tile) {
        const int tile_pid = base_pt + tile * 16;

        // ---- stage all 4 points of this wave's rows: 128 entries, 2 per lane ----
        #pragma unroll
        for (int e = 0; e < 2; ++e) {
            int ent = lane + e * 64;
            int j = ent >> 5, k = ent & 31;
            int pid = tile_pid + wv * 4 + j;
            int b   = pid >> 14;
            int nb  = NB[(size_t)pid * KNB + k];
            int gidx = b * MPTS + nb;
            const float* xn = X + (size_t)gidx * 3;
            const float* xc = X + (size_t)pid * 3;
            float4 v;
            v.x = xn[0] - xc[0];
            v.y = xn[1] - xc[1];
            v.z = xn[2] - xc[2];
            v.w = __int_as_float(gidx);
            stg[wv][j][k] = v;   // same-wave produce/consume: lgkmcnt orders it
        }

        // ---------------- stage 1: 4 points per wave ----------------
        for (int j = 0; j < 4; ++j) {
            const int row = wv * 4 + j;          // Fk row within tile

            bf16x8 ah;
            int nbs[8];
            #pragma unroll
            for (int i = 0; i < 8; ++i) {
                float4 rv = stg[wv][j][g16 * 8 + i];
                nbs[i] = __float_as_int(rv.w);
                float dx = rv.x - qx, dy = rv.y - qy, dz = rv.z - qz;
                float d2 = fmaf(dx, dx, fmaf(dy, dy, dz * dz));
                float h  = 1.f - sqrtf(d2);
                h = (pvalid && h > 0.f) ? h : 0.f;
                ah[i] = (__bf16)h;
            }

            f32x4 acc[4];
            #pragma unroll
            for (int t = 0; t < 4; ++t) {
                bf16x8 bf;
                #pragma unroll
                for (int i = 0; i < 8; ++i)
                    bf[i] = loadF(F, (size_t)nbs[i] * DIN + t * 16 + r16);
                f32x4 zero = {0.f, 0.f, 0.f, 0.f};
                acc[t] = __builtin_amdgcn_mfma_f32_16x16x32_bf16(ah, bf, zero, 0, 0, 0);
            }

            // write Fk row to LDS (bf16), XOR-swizzle on 16B chunks within the row
            #pragma unroll
            for (int t = 0; t < 4; ++t) {
                #pragma unroll
                for (int r = 0; r < 4; ++r) {
                    int p = g16 * 4 + r;         // D row = kernel point
                    if (p < KP) {
                        int pd    = p * DIN + t * 16 + r16;
                        int chunk = (pd >> 3) ^ (row & 7) ^ (p & 7);   // p == pd>>6
                        int off   = row * ROWBYTES + chunk * 16 + (pd & 7) * 2;
                        *reinterpret_cast<unsigned short*>(
                            reinterpret_cast<char*>(fk) + off) = f2b(acc[t][r]);
                    }
                }
            }
        }

        __syncthreads();   // all 16 Fk rows visible to all waves

        // ---------------- stage 2: [16 x 960] x [960 x 16] per wave ----------------
        f32x4 o = {0.f, 0.f, 0.f, 0.f};
        #pragma unroll
        for (int ks = 0; ks < KSTEPS; ++ks) {
            int chunk = (ks * 4 + g16) ^ (r16 & 7) ^ ((ks >> 1) & 7);  // ks>>1 == pd>>6
            bf16x8 a = *reinterpret_cast<const bf16x8*>(
                reinterpret_cast<const char*>(fk) + r16 * ROWBYTES + chunk * 16);
            o = __builtin_amdgcn_mfma_f32_16x16x32_bf16(a, bw[ks], o, 0, 0, 0);
        }

        #pragma unroll
        for (int r = 0; r < 4; ++r) {
            int prow = g16 * 4 + r;                  // D row = point within tile
            int pid  = tile_pid + prow;
            OUT[(size_t)pid * DOUT + wv * 16 + r16] = o[r];
        }

        __syncthreads();   // protect fk before next tile overwrites it
    }
}

extern "C" void kernel_launch(void* const* d_in, const int* in_sizes, int n_in,
                              void* d_out, int out_size, void* d_ws, size_t ws_size,
                              hipStream_t stream) {
    const float* X = (const float*)d_in[0];
    const float* F = (const float*)d_in[1];
    const int*   N = (const int*)d_in[2];
    const float* Q = (const float*)d_in[3];
    const float* W = (const float*)d_in[4];
    float* OUT = (float*)d_out;
    unsigned short* WB = (unsigned short*)d_ws;          // 122880 B
    unsigned short* FB = WB + WBELEMS;                   // 8388608 B (16B-aligned offset)

    const size_t need = (size_t)WBELEMS * 2 + (size_t)PTS * DIN * 2;

    prep_wb<<<(WBELEMS + 255) / 256, 256, 0, stream>>>(W, WB);

    if (ws_size >= need) {
        const int n8 = PTS * DIN / 8;                    // 524288
        f2bf_kernel<<<(n8 + 255) / 256, 256, 0, stream>>>(F, FB, n8);
        kpconv_main<unsigned short><<<NBLK, 256, 0, stream>>>(X, FB, N, Q, WB, OUT);
    } else {
        kpconv_main<float><<<NBLK, 256, 0, stream>>>(X, F, N, Q, WB, OUT);
    }
}

// Round 3
// 76.082 us; speedup vs baseline: 1.6749x; 1.6749x over previous
//
#include <hip/hip_runtime.h>
#include <hip/hip_bf16.h>

// KPConv fused kernel for MI355X (gfx950) — round 3.
// B=4, M=16384, K_NB=32, D_IN=64, D_OUT=64, K_PTS=15, SIGMA=1.
//
// Stage 1 (per point): h[k][p] = max(0, 1-|r_k - Q_p|), Fk = h^T · Fn  (1 MFMA per d-tile)
// Stage 2 (per 16-pt tile): out = Fk · W, K=960 = 30 MFMA k-steps.
//
// R3 changes vs R2: W fragments STREAMED from global inside stage-2 (L1-resident;
// opaque-pointer asm defeats LICM so they never become 120 live regs -> no spill);
// grid 2048 x 32 pts (8 blocks/CU queued, 4 resident); launch_bounds(256,4) now safe.

#define BATCH 4
#define MPTS  16384
#define KNB   32
#define DIN   64
#define DOUT  64
#define KP    15
#define K2    (KP*DIN)      // 960
#define KSTEPS (K2/32)      // 30
#define ROWBYTES (K2*2)     // 1920 bytes per Fk row (bf16)
#define PTS   (BATCH*MPTS)  // 65536
#define PPB   32            // points per block
#define NBLK  (PTS/PPB)     // 2048
#define NTILE (PPB/16)      // 2
#define WBELEMS (KP*DIN*DOUT)   // 61440 ushorts = 122880 B

typedef __bf16 bf16x8 __attribute__((ext_vector_type(8)));
typedef float  f32x4  __attribute__((ext_vector_type(4)));
typedef unsigned short u16x8 __attribute__((ext_vector_type(8)));

static __device__ __forceinline__ unsigned short f2b(float x) {
    __bf16 h = (__bf16)x;              // RNE convert
    return __builtin_bit_cast(unsigned short, h);
}

static __device__ __forceinline__ __bf16 loadF(const float* F, size_t i) {
    return (__bf16)F[i];
}
static __device__ __forceinline__ __bf16 loadF(const unsigned short* F, size_t i) {
    return __builtin_bit_cast(__bf16, F[i]);
}

// ---- prep: W [15][64][64] f32 -> bf16 B-fragments in ws ----
// wb[((etile*KSTEPS + kstep)*64 + lane)*8 + i] = W[k=kstep*32+(lane>>4)*8+i][e=etile*16+(lane&15)]
__global__ void prep_wb(const float* __restrict__ W, unsigned short* __restrict__ wb) {
    int idx = blockIdx.x * 256 + threadIdx.x;
    if (idx >= WBELEMS) return;
    int i    = idx & 7;
    int lane = (idx >> 3) & 63;
    int ks   = (idx >> 9) % KSTEPS;
    int et   = idx / (KSTEPS * 512);
    int k = ks * 32 + (lane >> 4) * 8 + i;
    int p = k >> 6;
    int d = k & 63;
    int e = et * 16 + (lane & 15);
    wb[idx] = f2b(W[(p * DIN + d) * DOUT + e]);
}

// ---- prep: F f32 -> bf16 (8 elems / thread) ----
__global__ void f2bf_kernel(const float* __restrict__ src, unsigned short* __restrict__ dst, int n8) {
    int i = blockIdx.x * 256 + threadIdx.x;
    if (i >= n8) return;
    const float4* s = reinterpret_cast<const float4*>(src) + (size_t)i * 2;
    float4 a = s[0], b = s[1];
    u16x8 o;
    o[0] = f2b(a.x); o[1] = f2b(a.y); o[2] = f2b(a.z); o[3] = f2b(a.w);
    o[4] = f2b(b.x); o[5] = f2b(b.y); o[6] = f2b(b.z); o[7] = f2b(b.w);
    *(reinterpret_cast<u16x8*>(dst) + i) = o;
}

template<typename FT>
__global__ __launch_bounds__(256, 4)
void kpconv_main(const float* __restrict__ X, const FT* __restrict__ F,
                 const int* __restrict__ NB, const float* __restrict__ Q,
                 const unsigned short* __restrict__ WB, float* __restrict__ OUT) {
    __shared__ float4 stg[4][4][KNB];         // [wave][point j][nb]: (rx,ry,rz, idx-bits)
    __shared__ unsigned short fk[16 * K2];    // 16 Fk rows, bf16, XOR-swizzled 16B chunks

    const int tid  = threadIdx.x;
    const int wv   = tid >> 6;    // wave 0..3 = e-tile
    const int lane = tid & 63;
    const int g16  = lane >> 4;   // 0..3
    const int r16  = lane & 15;   // 0..15

    // per-lane kernel-point constants (stage-1 A row p = r16; p=15 is the zero pad row)
    float qx = 0.f, qy = 0.f, qz = 0.f;
    const bool pvalid = (r16 < KP);
    if (pvalid) {
        qx = Q[r16 * 3 + 0]; qy = Q[r16 * 3 + 1]; qz = Q[r16 * 3 + 2];
    }

    // XCD-aware mapping: XCD (bid&7) owns points [xcd*8192, xcd*8192+8192) -> one batch/XCD
    const int bid     = blockIdx.x;
    const int base_pt = (bid & 7) * (PTS / 8) + (bid >> 3) * PPB;

    for (int tile = 0; tile < NTILE; ++tile) {
        const int tile_pid = base_pt + tile * 16;

        // ---- stage all 4 points of this wave's rows: 128 entries, 2 per lane ----
        #pragma unroll
        for (int e = 0; e < 2; ++e) {
            int ent = lane + e * 64;
            int j = ent >> 5, k = ent & 31;
            int pid = tile_pid + wv * 4 + j;
            int b   = pid >> 14;
            int nb  = NB[(size_t)pid * KNB + k];
            int gidx = b * MPTS + nb;
            const float* xn = X + (size_t)gidx * 3;
            const float* xc = X + (size_t)pid * 3;
            float4 v;
            v.x = xn[0] - xc[0];
            v.y = xn[1] - xc[1];
            v.z = xn[2] - xc[2];
            v.w = __int_as_float(gidx);
            stg[wv][j][k] = v;   // same-wave produce/consume: lgkmcnt orders it
        }

        // ---------------- stage 1: 4 points per wave ----------------
        for (int j = 0; j < 4; ++j) {
            const int row = wv * 4 + j;          // Fk row within tile

            bf16x8 ah;
            int nbs[8];
            #pragma unroll
            for (int i = 0; i < 8; ++i) {
                float4 rv = stg[wv][j][g16 * 8 + i];
                nbs[i] = __float_as_int(rv.w);
                float dx = rv.x - qx, dy = rv.y - qy, dz = rv.z - qz;
                float d2 = fmaf(dx, dx, fmaf(dy, dy, dz * dz));
                float h  = 1.f - sqrtf(d2);
                h = (pvalid && h > 0.f) ? h : 0.f;
                ah[i] = (__bf16)h;
            }

            f32x4 acc[4];
            #pragma unroll
            for (int t = 0; t < 4; ++t) {
                bf16x8 bf;
                #pragma unroll
                for (int i = 0; i < 8; ++i)
                    bf[i] = loadF(F, (size_t)nbs[i] * DIN + t * 16 + r16);
                f32x4 zero = {0.f, 0.f, 0.f, 0.f};
                acc[t] = __builtin_amdgcn_mfma_f32_16x16x32_bf16(ah, bf, zero, 0, 0, 0);
            }

            // write Fk row to LDS (bf16), XOR-swizzle on 16B chunks within the row
            #pragma unroll
            for (int t = 0; t < 4; ++t) {
                #pragma unroll
                for (int r = 0; r < 4; ++r) {
                    int p = g16 * 4 + r;         // D row = kernel point
                    if (p < KP) {
                        int pd    = p * DIN + t * 16 + r16;
                        int chunk = (pd >> 3) ^ (row & 7) ^ (p & 7);   // p == pd>>6
                        int off   = row * ROWBYTES + chunk * 16 + (pd & 7) * 2;
                        *reinterpret_cast<unsigned short*>(
                            reinterpret_cast<char*>(fk) + off) = f2b(acc[t][r]);
                    }
                }
            }
        }

        __syncthreads();   // all 16 Fk rows visible to all waves

        // ---------------- stage 2: [16 x 960] x [960 x 16] per wave ----------------
        // W fragments streamed from global each tile (L1-resident, 30 KB/wave slice).
        // Opaque asm stops LICM from hoisting 30x16B loads into 120 live registers.
        const unsigned short* wbp = WB + ((size_t)(wv * KSTEPS) * 64 + lane) * 8;
        asm volatile("" : "+v"(wbp));

        f32x4 o = {0.f, 0.f, 0.f, 0.f};
        #pragma unroll
        for (int ks = 0; ks < KSTEPS; ++ks) {
            int chunk = (ks * 4 + g16) ^ (r16 & 7) ^ ((ks >> 1) & 7);  // ks>>1 == pd>>6
            bf16x8 a = *reinterpret_cast<const bf16x8*>(
                reinterpret_cast<const char*>(fk) + r16 * ROWBYTES + chunk * 16);
            bf16x8 b = *reinterpret_cast<const bf16x8*>(wbp + ks * 512);
            o = __builtin_amdgcn_mfma_f32_16x16x32_bf16(a, b, o, 0, 0, 0);
        }

        #pragma unroll
        for (int r = 0; r < 4; ++r) {
            int prow = g16 * 4 + r;                  // D row = point within tile
            int pid  = tile_pid + prow;
            OUT[(size_t)pid * DOUT + wv * 16 + r16] = o[r];
        }

        __syncthreads();   // protect fk before next tile overwrites it
    }
}

extern "C" void kernel_launch(void* const* d_in, const int* in_sizes, int n_in,
                              void* d_out, int out_size, void* d_ws, size_t ws_size,
                              hipStream_t stream) {
    const float* X = (const float*)d_in[0];
    const float* F = (const float*)d_in[1];
    const int*   N = (const int*)d_in[2];
    const float* Q = (const float*)d_in[3];
    const float* W = (const float*)d_in[4];
    float* OUT = (float*)d_out;
    unsigned short* WB = (unsigned short*)d_ws;          // 122880 B
    unsigned short* FB = WB + WBELEMS;                   // 8388608 B (16B-aligned offset)

    const size_t need = (size_t)WBELEMS * 2 + (size_t)PTS * DIN * 2;

    prep_wb<<<(WBELEMS + 255) / 256, 256, 0, stream>>>(W, WB);

    if (ws_size >= need) {
        const int n8 = PTS * DIN / 8;                    // 524288
        f2bf_kernel<<<(n8 + 255) / 256, 256, 0, stream>>>(F, FB, n8);
        kpconv_main<unsigned short><<<NBLK, 256, 0, stream>>>(X, FB, N, Q, WB, OUT);
    } else {
        kpconv_main<float><<<NBLK, 256, 0, stream>>>(X, F, N, Q, WB, OUT);
    }
}

// Round 5
// 69.822 us; speedup vs baseline: 1.8251x; 1.0897x over previous
//
#include <hip/hip_runtime.h>
#include <hip/hip_bf16.h>

// KPConv fused kernel for MI355X (gfx950) — round 5.
// B=4, M=16384, K_NB=32, D_IN=64, D_OUT=64, K_PTS=15, SIGMA=1.
//
// Back to the verified R3 skeleton; two safe levers:
// (1) channel-permuted MFMA tiles: tile t column n <-> channel 4n+t, so each
//     neighbor gather is ONE aligned dwordx2 (4 channels) instead of 4 scalar
//     ushort loads. kappa = t*256 + n*16 + p (p padded to 16; W rows p=15 zero).
//     fk D-write: 4 accs -> 4 contiguous kappa -> one ds_write_b64 per t.
// (2) fused stage-2 over both 16-pt tiles: fk holds 32 rows (64 KB), single
//     __syncthreads per block, W streamed once for 2 tiles (2 MFMA per W load).

#define BATCH 4
#define MPTS  16384
#define KNB   32
#define DIN   64
#define DOUT  64
#define KP    15
#define K2P   1024          // padded K: kappa = t*256 + n*16 + p (d = 4n+t)
#define KSTEPS (K2P/32)     // 32
#define ROWB  (K2P*2)       // 2048 bytes per fk row
#define PTS   (BATCH*MPTS)  // 65536
#define PPB   32            // points per block
#define NBLK  (PTS/PPB)     // 2048
#define WBELEMS (K2P*DOUT)  // 65536 ushorts = 131072 B

typedef __bf16 bf16x8 __attribute__((ext_vector_type(8)));
typedef __bf16 bf16x4 __attribute__((ext_vector_type(4)));
typedef float  f32x4  __attribute__((ext_vector_type(4)));
typedef unsigned short u16x8 __attribute__((ext_vector_type(8)));

static __device__ __forceinline__ unsigned short f2b(float x) {
    __bf16 h = (__bf16)x;              // RNE convert
    return __builtin_bit_cast(unsigned short, h);
}

// ---- prep: W [15][64][64] f32 -> padded bf16 B-fragments ----
// wb[((et*KSTEPS+ks)*64+lane)*8+i] = B[kappa][e]; kappa=ks*32+(lane>>4)*8+i;
// t=kappa>>8, n=(kappa>>4)&15, p=kappa&15; d=4n+t; e=et*16+(lane&15); p==15 -> 0.
__global__ void prep_wb(const float* __restrict__ W, unsigned short* __restrict__ wb) {
    int idx = blockIdx.x * 256 + threadIdx.x;
    if (idx >= WBELEMS) return;
    int i    = idx & 7;
    int lane = (idx >> 3) & 63;
    int ks   = (idx >> 9) & 31;
    int et   = idx >> 14;
    int kap  = ks * 32 + ((lane >> 4) << 3) + i;
    int t = kap >> 8;
    int n = (kap >> 4) & 15;
    int p = kap & 15;
    int d = 4 * n + t;
    int e = et * 16 + (lane & 15);
    float v = (p < KP) ? W[(p * DIN + d) * DOUT + e] : 0.f;
    wb[idx] = f2b(v);
}

// ---- prep: F f32 -> bf16 (8 elems / thread) ----
__global__ void f2bf_kernel(const float* __restrict__ src, unsigned short* __restrict__ dst, int n8) {
    int i = blockIdx.x * 256 + threadIdx.x;
    if (i >= n8) return;
    const float4* s = reinterpret_cast<const float4*>(src) + (size_t)i * 2;
    float4 a = s[0], b = s[1];
    u16x8 o;
    o[0] = f2b(a.x); o[1] = f2b(a.y); o[2] = f2b(a.z); o[3] = f2b(a.w);
    o[4] = f2b(b.x); o[5] = f2b(b.y); o[6] = f2b(b.z); o[7] = f2b(b.w);
    *(reinterpret_cast<u16x8*>(dst) + i) = o;
}

__global__ __launch_bounds__(256, 2)
void kpconv_main(const float* __restrict__ X, const unsigned short* __restrict__ FB,
                 const int* __restrict__ NB, const float* __restrict__ Q,
                 const unsigned short* __restrict__ WB, float* __restrict__ OUT) {
    __shared__ unsigned short fk[32 * K2P];   // 65536 B: 32 rows x 1024 kappa, 16B-chunk XOR swizzle
    __shared__ float4 stg[4][4][KNB];         //  8192 B: (rx,ry,rz,|r|^2), per-wave private
    __shared__ int    idxs[4][4][KNB];        //  2048 B: global F row of neighbor

    const int tid  = threadIdx.x;
    const int wv   = tid >> 6;    // wave 0..3 = e-tile
    const int lane = tid & 63;
    const int g16  = lane >> 4;   // 0..3
    const int r16  = lane & 15;   // 0..15

    // per-lane kernel-point constants; p=15 pad row gets a far-away virtual point -> h=0
    float qx = 1.0e3f, qy = 0.f, qz = 0.f;
    if (r16 < KP) { qx = Q[r16 * 3 + 0]; qy = Q[r16 * 3 + 1]; qz = Q[r16 * 3 + 2]; }
    const float qq   = qx * qx + qy * qy + qz * qz;
    const float nq2x = -2.f * qx, nq2y = -2.f * qy, nq2z = -2.f * qz;

    // XCD-aware mapping: XCD (bid&7) owns one batch's 8192-point span
    const int bid     = blockIdx.x;
    const int base_pt = (bid & 7) * (PTS / 8) + (bid >> 3) * PPB;

    for (int tile = 0; tile < 2; ++tile) {
        const int tile_pid = base_pt + tile * 16;

        // ---- stage r-vectors + neighbor indices for this wave's 4 points ----
        #pragma unroll
        for (int e = 0; e < 2; ++e) {
            int ent = lane + e * 64;
            int j = ent >> 5, k = ent & 31;
            int pid = tile_pid + wv * 4 + j;
            int b   = pid >> 14;
            int nb  = NB[(size_t)pid * KNB + k];
            int gidx = b * MPTS + nb;
            const float* xn = X + (size_t)gidx * 3;
            const float* xc = X + (size_t)pid * 3;
            float rx = xn[0] - xc[0];
            float ry = xn[1] - xc[1];
            float rz = xn[2] - xc[2];
            float rr = fmaf(rx, rx, fmaf(ry, ry, rz * rz));
            stg[wv][j][k]  = make_float4(rx, ry, rz, rr);
            idxs[wv][j][k] = gidx;
        }

        // ---------------- stage 1: 4 points per wave ----------------
        #pragma unroll
        for (int j = 0; j < 4; ++j) {
            const int row = tile * 16 + wv * 4 + j;    // fk row (0..31)

            // gather: one dwordx2 per neighbor (channels 4*r16 .. 4*r16+3)
            union U { uint2 d; unsigned short s[4]; };
            U L[8];
            #pragma unroll
            for (int i = 0; i < 8; ++i) {
                int gi = idxs[wv][j][g16 * 8 + i];
                L[i].d = *reinterpret_cast<const uint2*>(FB + ((size_t)gi << 6) + (r16 << 2));
            }

            // A fragment: h(p=r16, k=g16*8+i), dot-form d^2
            bf16x8 ah;
            #pragma unroll
            for (int i = 0; i < 8; ++i) {
                float4 rv = stg[wv][j][g16 * 8 + i];
                float d2 = fmaf(rv.x, nq2x, fmaf(rv.y, nq2y, fmaf(rv.z, nq2z, rv.w + qq)));
                d2 = fmaxf(d2, 0.f);
                ah[i] = (__bf16)fmaxf(1.f - sqrtf(d2), 0.f);
            }

            const f32x4 z = {0.f, 0.f, 0.f, 0.f};
            f32x4 accs[4];
            #pragma unroll
            for (int t = 0; t < 4; ++t) {
                bf16x8 bf;
                #pragma unroll
                for (int i = 0; i < 8; ++i)
                    bf[i] = __builtin_bit_cast(__bf16, L[i].s[t]);
                accs[t] = __builtin_amdgcn_mfma_f32_16x16x32_bf16(ah, bf, z, 0, 0, 0);
            }

            // fk write: D_t[p=g16*4+r][n=r16] -> kappa = t*256 + r16*16 + g16*4 + r
            // (4 contiguous kappa = one 8B write); 16B-chunk XOR swizzle by row&7
            #pragma unroll
            for (int t = 0; t < 4; ++t) {
                bf16x4 w4;
                w4[0] = (__bf16)accs[t][0];
                w4[1] = (__bf16)accs[t][1];
                w4[2] = (__bf16)accs[t][2];
                w4[3] = (__bf16)accs[t][3];
                int c   = t * 32 + r16 * 2 + (g16 >> 1);           // 16B chunk in row
                int off = row * ROWB + ((c ^ (row & 7)) << 4) + ((g16 & 1) << 3);
                *reinterpret_cast<bf16x4*>(reinterpret_cast<char*>(fk) + off) = w4;
            }
        }
    }

    __syncthreads();   // all 32 fk rows visible to all waves

    // ---------------- stage 2 (fused over both tiles) ----------------
    // [32 x 1024] x [1024 x 16] per wave; W streamed from L1 once for 2 tiles.
    const unsigned short* wbp = WB + ((size_t)(wv * KSTEPS) * 64 + lane) * 8;
    asm volatile("" : "+v"(wbp));   // defeat LICM: stream W, don't hold 128 regs

    f32x4 o0 = {0.f, 0.f, 0.f, 0.f};
    f32x4 o1 = {0.f, 0.f, 0.f, 0.f};
    #pragma unroll
    for (int ks = 0; ks < KSTEPS; ++ks) {
        bf16x8 b = *reinterpret_cast<const bf16x8*>(wbp + ks * 512);
        int c0 = (ks * 4 + g16) ^ (r16 & 7);
        bf16x8 a0 = *reinterpret_cast<const bf16x8*>(
            reinterpret_cast<const char*>(fk) + r16 * ROWB + (c0 << 4));
        bf16x8 a1 = *reinterpret_cast<const bf16x8*>(
            reinterpret_cast<const char*>(fk) + (16 + r16) * ROWB + (c0 << 4));
        o0 = __builtin_amdgcn_mfma_f32_16x16x32_bf16(a0, b, o0, 0, 0, 0);
        o1 = __builtin_amdgcn_mfma_f32_16x16x32_bf16(a1, b, o1, 0, 0, 0);
    }

    #pragma unroll
    for (int r = 0; r < 4; ++r) {
        int p0 = base_pt + g16 * 4 + r;
        OUT[(size_t)p0 * DOUT + wv * 16 + r16] = o0[r];
        int p1 = base_pt + 16 + g16 * 4 + r;
        OUT[(size_t)p1 * DOUT + wv * 16 + r16] = o1[r];
    }
}

extern "C" void kernel_launch(void* const* d_in, const int* in_sizes, int n_in,
                              void* d_out, int out_size, void* d_ws, size_t ws_size,
                              hipStream_t stream) {
    const float* X = (const float*)d_in[0];
    const float* F = (const float*)d_in[1];
    const int*   N = (const int*)d_in[2];
    const float* Q = (const float*)d_in[3];
    const float* W = (const float*)d_in[4];
    float* OUT = (float*)d_out;
    unsigned short* WB = (unsigned short*)d_ws;          // 131072 B
    unsigned short* FB = WB + WBELEMS;                   // 8388608 B

    prep_wb<<<(WBELEMS + 255) / 256, 256, 0, stream>>>(W, WB);

    const int n8 = PTS * DIN / 8;                        // 524288
    f2bf_kernel<<<(n8 + 255) / 256, 256, 0, stream>>>(F, FB, n8);

    kpconv_main<<<NBLK, 256, 0, stream>>>(X, FB, N, Q, WB, OUT);
}

// Round 6
// 66.007 us; speedup vs baseline: 1.9305x; 1.0578x over previous
//
#include <hip/hip_runtime.h>
#include <hip/hip_bf16.h>

// KPConv fused kernel for MI355X (gfx950) — round 6.
// B=4, M=16384, K_NB=32, D_IN=64, D_OUT=64, K_PTS=15, SIGMA=1.
//
// R6 vs R5:
//  * PPB=16 (grid 4096), fk 16 rows -> LDS 40960 B -> 4 blocks/CU (occupancy 2x).
//  * kappa = n*64 + (p>>2)*16 + t*4 + (p&3): lane's 16 D-values are 32 contiguous
//    bytes -> fk write = 2x ds_write_b128 with swizzle c ^ (row&7) ^ ((c>>3)&7)
//    (conflict-free both sides; read side adds ^((ks>>1)&7)).
//  * stg slot swizzle s(k) = (k&24)|((k^(k>>3))&7) kills the 4-way stg-read conflict.
//  * gidx packed in stg.w (fits u16 range but stored as int bits); rr recomputed.

#define BATCH 4
#define MPTS  16384
#define KNB   32
#define DIN   64
#define DOUT  64
#define KP    15
#define K2P   1024          // padded K: kappa = n*64 + (p>>2)*16 + t*4 + (p&3), d = 4n+t
#define KSTEPS (K2P/32)     // 32
#define ROWB  (K2P*2)       // 2048 bytes per fk row
#define PTS   (BATCH*MPTS)  // 65536
#define PPB   16            // points per block
#define NBLK  (PTS/PPB)     // 4096
#define WBELEMS (K2P*DOUT)  // 65536 ushorts = 131072 B

typedef __bf16 bf16x8 __attribute__((ext_vector_type(8)));
typedef float  f32x4  __attribute__((ext_vector_type(4)));
typedef unsigned short u16x8 __attribute__((ext_vector_type(8)));

static __device__ __forceinline__ unsigned short f2b(float x) {
    __bf16 h = (__bf16)x;              // RNE convert
    return __builtin_bit_cast(unsigned short, h);
}

// ---- prep: W [15][64][64] f32 -> padded bf16 B-fragments ----
// wb[((et*KSTEPS+ks)*64+lane)*8+i] = B[kappa][e]; kappa=ks*32+(lane>>4)*8+i;
// n=kap>>6, g=(kap>>4)&3, t=(kap>>2)&3, r=kap&3; p=4g+r, d=4n+t; p==15 -> 0.
__global__ void prep_wb(const float* __restrict__ W, unsigned short* __restrict__ wb) {
    int idx = blockIdx.x * 256 + threadIdx.x;
    if (idx >= WBELEMS) return;
    int i    = idx & 7;
    int lane = (idx >> 3) & 63;
    int ks   = (idx >> 9) & 31;
    int et   = idx >> 14;
    int kap  = ks * 32 + ((lane >> 4) << 3) + i;
    int n = kap >> 6;
    int g = (kap >> 4) & 3;
    int t = (kap >> 2) & 3;
    int r = kap & 3;
    int p = g * 4 + r;
    int d = n * 4 + t;
    int e = et * 16 + (lane & 15);
    float v = (p < KP) ? W[(p * DIN + d) * DOUT + e] : 0.f;
    wb[idx] = f2b(v);
}

// ---- prep: F f32 -> bf16 (8 elems / thread) ----
__global__ void f2bf_kernel(const float* __restrict__ src, unsigned short* __restrict__ dst, int n8) {
    int i = blockIdx.x * 256 + threadIdx.x;
    if (i >= n8) return;
    const float4* s = reinterpret_cast<const float4*>(src) + (size_t)i * 2;
    float4 a = s[0], b = s[1];
    u16x8 o;
    o[0] = f2b(a.x); o[1] = f2b(a.y); o[2] = f2b(a.z); o[3] = f2b(a.w);
    o[4] = f2b(b.x); o[5] = f2b(b.y); o[6] = f2b(b.z); o[7] = f2b(b.w);
    *(reinterpret_cast<u16x8*>(dst) + i) = o;
}

__global__ __launch_bounds__(256, 4)
void kpconv_main(const float* __restrict__ X, const unsigned short* __restrict__ FB,
                 const int* __restrict__ NB, const float* __restrict__ Q,
                 const unsigned short* __restrict__ WB, float* __restrict__ OUT) {
    __shared__ unsigned short fk[16 * K2P];   // 32768 B: 16 rows x 1024 kappa, swizzled 16B chunks
    __shared__ float4 stg[4][4][KNB];         //  8192 B: (rx,ry,rz, idx-bits), slot-swizzled

    const int tid  = threadIdx.x;
    const int wv   = tid >> 6;    // wave 0..3 = e-tile
    const int lane = tid & 63;
    const int g16  = lane >> 4;   // 0..3
    const int r16  = lane & 15;   // 0..15

    // per-lane kernel-point constants; p=15 pad row gets far-away virtual point -> h=0
    float qx = 1.0e3f, qy = 0.f, qz = 0.f;
    if (r16 < KP) { qx = Q[r16 * 3 + 0]; qy = Q[r16 * 3 + 1]; qz = Q[r16 * 3 + 2]; }

    // XCD-aware mapping: XCD (bid&7) owns one batch's 8192-point span
    const int bid     = blockIdx.x;
    const int base_pt = (bid & 7) * (PTS / 8) + (bid >> 3) * PPB;

    // ---- stage r-vectors + neighbor idx (packed in .w); slot-swizzled ----
    #pragma unroll
    for (int e = 0; e < 2; ++e) {
        int ent = lane + e * 64;
        int j = ent >> 5, k = ent & 31;
        int pid = base_pt + wv * 4 + j;
        int b   = pid >> 14;
        int nb  = NB[(size_t)pid * KNB + k];
        int gidx = b * MPTS + nb;
        const float* xn = X + (size_t)gidx * 3;
        const float* xc = X + (size_t)pid * 3;
        float4 v;
        v.x = xn[0] - xc[0];
        v.y = xn[1] - xc[1];
        v.z = xn[2] - xc[2];
        v.w = __int_as_float(gidx);
        int slot = (k & 24) | ((k ^ (k >> 3)) & 7);
        stg[wv][j][slot] = v;   // same-wave produce/consume: lgkmcnt orders it
    }

    // ---------------- stage 1: 4 points per wave ----------------
    #pragma unroll
    for (int j = 0; j < 4; ++j) {
        const int row = wv * 4 + j;                // fk row (0..15)

        // read this lane's 8 neighbor entries (slot-swizzled: a=g16 fixed, b=i)
        float4 rv[8];
        #pragma unroll
        for (int i = 0; i < 8; ++i)
            rv[i] = stg[wv][j][g16 * 8 + (i ^ g16)];

        // gather: one dwordx2 per neighbor (channels 4*r16 .. 4*r16+3)
        union U { uint2 d; unsigned short s[4]; };
        U L[8];
        #pragma unroll
        for (int i = 0; i < 8; ++i) {
            int gi = __float_as_int(rv[i].w);
            L[i].d = *reinterpret_cast<const uint2*>(FB + ((size_t)gi << 6) + (r16 << 2));
        }

        // A fragment: h(p=r16, k=g16*8+i), direct-form d^2 (>=0 by construction)
        bf16x8 ah;
        #pragma unroll
        for (int i = 0; i < 8; ++i) {
            float dx = rv[i].x - qx, dy = rv[i].y - qy, dz = rv[i].z - qz;
            float d2 = fmaf(dx, dx, fmaf(dy, dy, dz * dz));
            ah[i] = (__bf16)fmaxf(1.f - sqrtf(d2), 0.f);
        }

        const f32x4 z = {0.f, 0.f, 0.f, 0.f};
        f32x4 accs[4];
        #pragma unroll
        for (int t = 0; t < 4; ++t) {
            bf16x8 bf;
            #pragma unroll
            for (int i = 0; i < 8; ++i)
                bf[i] = __builtin_bit_cast(__bf16, L[i].s[t]);
            accs[t] = __builtin_amdgcn_mfma_f32_16x16x32_bf16(ah, bf, z, 0, 0, 0);
        }

        // fk write: lane holds kappa r16*64+g16*16 .. +15 (32 B) -> 2x ds_write_b128
        // stored chunk = c ^ (row&7) ^ ((c>>3)&7);  c = r16*8 + g16*2 + h, c>>3 = r16
        bf16x8 w0, w1;
        #pragma unroll
        for (int r = 0; r < 4; ++r) {
            w0[r]     = (__bf16)accs[0][r];
            w0[4 + r] = (__bf16)accs[1][r];
            w1[r]     = (__bf16)accs[2][r];
            w1[4 + r] = (__bf16)accs[3][r];
        }
        int swz  = (row & 7) ^ (r16 & 7);
        int off0 = row * ROWB + (r16 * 8 + ((g16 * 2 + 0) ^ swz)) * 16;
        int off1 = row * ROWB + (r16 * 8 + ((g16 * 2 + 1) ^ swz)) * 16;
        *reinterpret_cast<bf16x8*>(reinterpret_cast<char*>(fk) + off0) = w0;
        *reinterpret_cast<bf16x8*>(reinterpret_cast<char*>(fk) + off1) = w1;
    }

    __syncthreads();   // all 16 fk rows visible to all waves

    // ---------------- stage 2: [16 x 1024] x [1024 x 16] per wave ----------------
    const unsigned short* wbp = WB + ((size_t)(wv * KSTEPS) * 64 + lane) * 8;
    asm volatile("" : "+v"(wbp));   // defeat LICM: stream W from L1/L2, not 128 regs

    f32x4 o = {0.f, 0.f, 0.f, 0.f};
    #pragma unroll
    for (int ks = 0; ks < KSTEPS; ++ks) {
        bf16x8 b = *reinterpret_cast<const bf16x8*>(wbp + ks * 512);
        int stored = (ks * 4 + g16) ^ (r16 & 7) ^ ((ks >> 1) & 7);
        bf16x8 a = *reinterpret_cast<const bf16x8*>(
            reinterpret_cast<const char*>(fk) + r16 * ROWB + stored * 16);
        o = __builtin_amdgcn_mfma_f32_16x16x32_bf16(a, b, o, 0, 0, 0);
    }

    #pragma unroll
    for (int r = 0; r < 4; ++r) {
        int pid = base_pt + g16 * 4 + r;
        OUT[(size_t)pid * DOUT + wv * 16 + r16] = o[r];
    }
}

extern "C" void kernel_launch(void* const* d_in, const int* in_sizes, int n_in,
                              void* d_out, int out_size, void* d_ws, size_t ws_size,
                              hipStream_t stream) {
    const float* X = (const float*)d_in[0];
    const float* F = (const float*)d_in[1];
    const int*   N = (const int*)d_in[2];
    const float* Q = (const float*)d_in[3];
    const float* W = (const float*)d_in[4];
    float* OUT = (float*)d_out;
    unsigned short* WB = (unsigned short*)d_ws;          // 131072 B
    unsigned short* FB = WB + WBELEMS;                   // 8388608 B

    prep_wb<<<(WBELEMS + 255) / 256, 256, 0, stream>>>(W, WB);

    const int n8 = PTS * DIN / 8;                        // 524288
    f2bf_kernel<<<(n8 + 255) / 256, 256, 0, stream>>>(F, FB, n8);

    kpconv_main<<<NBLK, 256, 0, stream>>>(X, FB, N, Q, WB, OUT);
}

// Round 7
// 63.448 us; speedup vs baseline: 2.0084x; 1.0403x over previous
//
#include <hip/hip_runtime.h>
#include <hip/hip_bf16.h>

// KPConv fused kernel for MI355X (gfx950) — round 7.
// B=4, M=16384, K_NB=32, D_IN=64, D_OUT=64, K_PTS=15, SIGMA=1.
//
// R7 vs R6 (both passed, R6 = 56 us kernel):
//  * F-gather decoupled from the X/LDS chain: per-lane NB via 2x int4 loads,
//    gidx in registers, gathers issued at wave start and 2-deep software-
//    pipelined across the 4 points (L[2][8] double buffer).
//  * __builtin_amdgcn_sqrtf for h (1 instr vs libm chain).
//  * Same verified layouts/swizzles as R6: kappa = n*64+(p>>2)*16+t*4+(p&3),
//    fk chunk swizzle c^(row&7)^((c>>3)&7), stg slot swizzle, XCD mapping.

#define BATCH 4
#define MPTS  16384
#define KNB   32
#define DIN   64
#define DOUT  64
#define KP    15
#define K2P   1024          // padded K: kappa = n*64 + (p>>2)*16 + t*4 + (p&3), d = 4n+t
#define KSTEPS (K2P/32)     // 32
#define ROWB  (K2P*2)       // 2048 bytes per fk row
#define PTS   (BATCH*MPTS)  // 65536
#define PPB   16            // points per block
#define NBLK  (PTS/PPB)     // 4096
#define WBELEMS (K2P*DOUT)  // 65536 ushorts = 131072 B

typedef __bf16 bf16x8 __attribute__((ext_vector_type(8)));
typedef float  f32x4  __attribute__((ext_vector_type(4)));
typedef unsigned short u16x8 __attribute__((ext_vector_type(8)));

static __device__ __forceinline__ unsigned short f2b(float x) {
    __bf16 h = (__bf16)x;              // RNE convert
    return __builtin_bit_cast(unsigned short, h);
}

// ---- prep: W [15][64][64] f32 -> padded bf16 B-fragments ----
// wb[((et*KSTEPS+ks)*64+lane)*8+i] = B[kappa][e]; kappa=ks*32+(lane>>4)*8+i;
// n=kap>>6, g=(kap>>4)&3, t=(kap>>2)&3, r=kap&3; p=4g+r, d=4n+t; p==15 -> 0.
__global__ void prep_wb(const float* __restrict__ W, unsigned short* __restrict__ wb) {
    int idx = blockIdx.x * 256 + threadIdx.x;
    if (idx >= WBELEMS) return;
    int i    = idx & 7;
    int lane = (idx >> 3) & 63;
    int ks   = (idx >> 9) & 31;
    int et   = idx >> 14;
    int kap  = ks * 32 + ((lane >> 4) << 3) + i;
    int n = kap >> 6;
    int g = (kap >> 4) & 3;
    int t = (kap >> 2) & 3;
    int r = kap & 3;
    int p = g * 4 + r;
    int d = n * 4 + t;
    int e = et * 16 + (lane & 15);
    float v = (p < KP) ? W[(p * DIN + d) * DOUT + e] : 0.f;
    wb[idx] = f2b(v);
}

// ---- prep: F f32 -> bf16 (8 elems / thread) ----
__global__ void f2bf_kernel(const float* __restrict__ src, unsigned short* __restrict__ dst, int n8) {
    int i = blockIdx.x * 256 + threadIdx.x;
    if (i >= n8) return;
    const float4* s = reinterpret_cast<const float4*>(src) + (size_t)i * 2;
    float4 a = s[0], b = s[1];
    u16x8 o;
    o[0] = f2b(a.x); o[1] = f2b(a.y); o[2] = f2b(a.z); o[3] = f2b(a.w);
    o[4] = f2b(b.x); o[5] = f2b(b.y); o[6] = f2b(b.z); o[7] = f2b(b.w);
    *(reinterpret_cast<u16x8*>(dst) + i) = o;
}

__global__ __launch_bounds__(256, 4)
void kpconv_main(const float* __restrict__ X, const unsigned short* __restrict__ FB,
                 const int* __restrict__ NB, const float* __restrict__ Q,
                 const unsigned short* __restrict__ WB, float* __restrict__ OUT) {
    __shared__ unsigned short fk[16 * K2P];   // 32768 B: 16 rows x 1024 kappa, swizzled 16B chunks
    __shared__ float4 stg[4][4][KNB];         //  8192 B: (rx,ry,rz,|r|^2), slot-swizzled

    const int tid  = threadIdx.x;
    const int wv   = tid >> 6;    // wave 0..3 = e-tile
    const int lane = tid & 63;
    const int g16  = lane >> 4;   // 0..3
    const int r16  = lane & 15;   // 0..15

    // per-lane kernel-point constants; p=15 pad row gets far-away virtual point -> h=0
    float qx = 1.0e3f, qy = 0.f, qz = 0.f;
    if (r16 < KP) { qx = Q[r16 * 3 + 0]; qy = Q[r16 * 3 + 1]; qz = Q[r16 * 3 + 2]; }
    const float qq   = qx * qx + qy * qy + qz * qz;
    const float nq2x = -2.f * qx, nq2y = -2.f * qy, nq2z = -2.f * qz;

    // XCD-aware mapping: XCD (bid&7) owns one batch's 8192-point span
    const int bid     = blockIdx.x;
    const int base_pt = (bid & 7) * (PTS / 8) + (bid >> 3) * PPB;
    const int boff    = (base_pt >> 14) * MPTS;   // uniform per block
    const int pid0    = base_pt + wv * 4;

    // ---- stage r-vectors (rx,ry,rz,|r|^2), slot-swizzled; independent of gathers ----
    #pragma unroll
    for (int e = 0; e < 2; ++e) {
        int ent = lane + e * 64;
        int j = ent >> 5, k = ent & 31;
        int pid = pid0 + j;
        int nb  = NB[(size_t)pid * KNB + k];
        int gidx = boff + nb;
        const float* xn = X + (size_t)gidx * 3;
        const float* xc = X + (size_t)pid * 3;
        float rx = xn[0] - xc[0];
        float ry = xn[1] - xc[1];
        float rz = xn[2] - xc[2];
        float rr = fmaf(rx, rx, fmaf(ry, ry, rz * rz));
        int slot = (k & 24) | ((k ^ (k >> 3)) & 7);
        stg[wv][j][slot] = make_float4(rx, ry, rz, rr);   // same-wave produce/consume
    }

    // ---- 2-deep pipelined F gathers: lane owns neighbors g16*8..+7, channels 4*r16..+3 ----
    union U { uint2 d; unsigned short s[4]; };
    U L[2][8];

    auto issue_gather = [&](int j, U* Lj) {
        const int* nbp = NB + (size_t)(pid0 + j) * KNB + g16 * 8;
        int4 a = *reinterpret_cast<const int4*>(nbp);
        int4 b = *reinterpret_cast<const int4*>(nbp + 4);
        int g[8] = {a.x, a.y, a.z, a.w, b.x, b.y, b.z, b.w};
        #pragma unroll
        for (int i = 0; i < 8; ++i)
            Lj[i].d = *reinterpret_cast<const uint2*>(
                FB + ((size_t)(boff + g[i]) << 6) + (r16 << 2));
    };

    issue_gather(0, L[0]);
    issue_gather(1, L[1]);

    // ---------------- stage 1: 4 points per wave, pipelined ----------------
    #pragma unroll
    for (int j = 0; j < 4; ++j) {
        const int row = wv * 4 + j;                // fk row (0..15)

        // A fragment: h(p=r16, k=g16*8+i), dot-form d^2 clamped to 0
        bf16x8 ah;
        #pragma unroll
        for (int i = 0; i < 8; ++i) {
            float4 rv = stg[wv][j][g16 * 8 + (i ^ g16)];
            float d2 = fmaf(rv.x, nq2x, fmaf(rv.y, nq2y, fmaf(rv.z, nq2z, rv.w + qq)));
            d2 = fmaxf(d2, 0.f);
            ah[i] = (__bf16)fmaxf(1.f - __builtin_amdgcn_sqrtf(d2), 0.f);
        }

        // extract B fragments from this j's gather buffer, then reuse it for j+2
        bf16x8 bfr[4];
        #pragma unroll
        for (int t = 0; t < 4; ++t)
            #pragma unroll
            for (int i = 0; i < 8; ++i)
                bfr[t][i] = __builtin_bit_cast(__bf16, L[j & 1][i].s[t]);

        if (j < 2) issue_gather(j + 2, L[j & 1]);

        const f32x4 z = {0.f, 0.f, 0.f, 0.f};
        f32x4 accs[4];
        #pragma unroll
        for (int t = 0; t < 4; ++t)
            accs[t] = __builtin_amdgcn_mfma_f32_16x16x32_bf16(ah, bfr[t], z, 0, 0, 0);

        // fk write: lane holds kappa r16*64+g16*16 .. +15 (32 B) -> 2x ds_write_b128
        bf16x8 w0, w1;
        #pragma unroll
        for (int r = 0; r < 4; ++r) {
            w0[r]     = (__bf16)accs[0][r];
            w0[4 + r] = (__bf16)accs[1][r];
            w1[r]     = (__bf16)accs[2][r];
            w1[4 + r] = (__bf16)accs[3][r];
        }
        int swz  = (row & 7) ^ (r16 & 7);
        int off0 = row * ROWB + (r16 * 8 + ((g16 * 2 + 0) ^ swz)) * 16;
        int off1 = row * ROWB + (r16 * 8 + ((g16 * 2 + 1) ^ swz)) * 16;
        *reinterpret_cast<bf16x8*>(reinterpret_cast<char*>(fk) + off0) = w0;
        *reinterpret_cast<bf16x8*>(reinterpret_cast<char*>(fk) + off1) = w1;
    }

    __syncthreads();   // all 16 fk rows visible to all waves

    // ---------------- stage 2: [16 x 1024] x [1024 x 16] per wave ----------------
    const unsigned short* wbp = WB + ((size_t)(wv * KSTEPS) * 64 + lane) * 8;
    asm volatile("" : "+v"(wbp));   // defeat LICM: stream W from L1/L2, not 128 regs

    f32x4 o = {0.f, 0.f, 0.f, 0.f};
    #pragma unroll
    for (int ks = 0; ks < KSTEPS; ++ks) {
        bf16x8 b = *reinterpret_cast<const bf16x8*>(wbp + ks * 512);
        int stored = (ks * 4 + g16) ^ (r16 & 7) ^ ((ks >> 1) & 7);
        bf16x8 a = *reinterpret_cast<const bf16x8*>(
            reinterpret_cast<const char*>(fk) + r16 * ROWB + stored * 16);
        o = __builtin_amdgcn_mfma_f32_16x16x32_bf16(a, b, o, 0, 0, 0);
    }

    #pragma unroll
    for (int r = 0; r < 4; ++r) {
        int pid = base_pt + g16 * 4 + r;
        OUT[(size_t)pid * DOUT + wv * 16 + r16] = o[r];
    }
}

extern "C" void kernel_launch(void* const* d_in, const int* in_sizes, int n_in,
                              void* d_out, int out_size, void* d_ws, size_t ws_size,
                              hipStream_t stream) {
    const float* X = (const float*)d_in[0];
    const float* F = (const float*)d_in[1];
    const int*   N = (const int*)d_in[2];
    const float* Q = (const float*)d_in[3];
    const float* W = (const float*)d_in[4];
    float* OUT = (float*)d_out;
    unsigned short* WB = (unsigned short*)d_ws;          // 131072 B
    unsigned short* FB = WB + WBELEMS;                   // 8388608 B

    prep_wb<<<(WBELEMS + 255) / 256, 256, 0, stream>>>(W, WB);

    const int n8 = PTS * DIN / 8;                        // 524288
    f2bf_kernel<<<(n8 + 255) / 256, 256, 0, stream>>>(F, FB, n8);

    kpconv_main<<<NBLK, 256, 0, stream>>>(X, FB, N, Q, WB, OUT);
}